// Round 10
// baseline (59.857 us; speedup 1.0000x reference)
//
#include <hip/hip_runtime.h>
#include <hip/hip_fp16.h>

// Problem constants (must match reference)
#define NUM_PHYSICAL 2000000
#define NUM_NODES    2500000   // 2,000,000 physical + 500,000 filler
#define NBX 512
#define NBY 512
#define NBINS (NBX * NBY)

// BSX = BSY = 1000/512 = 1.953125 (exact in binary)
#define BSX 1.953125f
#define HALF_STRETCH ((float)(0.5 * 1.953125 * 1.4142135623730951))
// BSX*BSY*UNIT_PIN_CAPACITY = 61.03515625 (exact); x 65536 = 4,000,000 exactly
#define INV_Q_NORM (1.0f / 4000000.0f)
#define NORM_DIV 61.03515625f
#define MAX_RATE 2.5f
#define MIN_RATE 0.4f   // 1/2.5 exactly

// Strip bucketing: 64 strips of 8 y-rows each, fixed-capacity regions.
#define NSTRIP 64
#define SCAP 49152               // slots per strip (~+98 sigma над 31.7K mean)
#define SROWS 8                  // rows per strip
#define LROWS 10                 // 8 + 2 y-halo (node spans <=3 rows)
#define SCELLS (NBX * LROWS)     // 5120 u32 = 20 KB LDS, col-major [col][row]
#define RREP 8                   // scatter replicas per strip
#define SCAT_BLOCKS (NSTRIP * RREP)
#define SCAT_THREADS 1024
#define HB 1024                  // blocks for fused placement
#define CHUNK ((NUM_PHYSICAL + HB - 1) / HB)   // 1954

__device__ __forceinline__ int strip_of(float y_min) {
    int byl = (int)floorf(y_min / BSX);
    return (min(max(byl, 0), NBY - 1)) >> 3;
}

__device__ __forceinline__ void node_box(const float* __restrict__ pos,
                                         const float* __restrict__ nsx,
                                         const float* __restrict__ nsy, int i,
                                         float& x_min, float& y_min,
                                         float& hx, float& hy) {
    float sx = nsx[i], sy = nsy[i];
    hx = 0.5f * fmaxf(sx, 2.0f * HALF_STRETCH);
    hy = 0.5f * fmaxf(sy, 2.0f * HALF_STRETCH);
    x_min = (pos[i]             + 0.5f * sx) - hx;
    y_min = (pos[NUM_NODES + i] + 0.5f * sy) - hy;
}

__device__ __forceinline__ float pack_hxy(float hx, float hy) {
    unsigned int u = ((unsigned int)__half_as_ushort(__float2half_rn(hy)) << 16)
                   |  (unsigned int)__half_as_ushort(__float2half_rn(hx));
    return __uint_as_float(u);
}
__device__ __forceinline__ void unpack_hxy(float p, float& hx, float& hy) {
    unsigned int u = __float_as_uint(p);
    hx = __half2float(__ushort_as_half((unsigned short)(u & 0xffffu)));
    hy = __half2float(__ushort_as_half((unsigned short)(u >> 16)));
}

// ---------------- sorted-strip path ----------------

// K1 (fused hist+place): pass 1 builds per-block strip histogram from the
// block's L1-resident chunk; one global atomicAdd per strip reserves a range
// in the strip's fixed-capacity region; pass 2 writes 16B payloads.
// Payload order within a strip is nondeterministic across blocks, but the
// downstream accumulation is integer (exact, commutative) so d_out is
// bit-deterministic anyway.
__global__ __launch_bounds__(256) void place_fused_kernel(
        const float* __restrict__ pos, const float* __restrict__ nsx,
        const float* __restrict__ nsy, const float* __restrict__ pw,
        unsigned int* __restrict__ strip_count,   // [NSTRIP], pre-zeroed
        float4* __restrict__ pay) {
    __shared__ int lh[NSTRIP];     // pass1: counts; pass2: local cursor
    __shared__ int lbase[NSTRIP];  // global base reserved for this block
    int tid = threadIdx.x, b = blockIdx.x;
    if (tid < NSTRIP) lh[tid] = 0;
    __syncthreads();
    int lo = b * CHUNK, hi = min(lo + CHUNK, NUM_PHYSICAL);
    // pass 1: strip needs only y data (16 KB/chunk -> L1-resident for pass 2)
    for (int i = lo + tid; i < hi; i += 256) {
        float sy = nsy[i];
        float hy = 0.5f * fmaxf(sy, 2.0f * HALF_STRETCH);
        float y_min = (pos[NUM_NODES + i] + 0.5f * sy) - hy;
        atomicAdd(&lh[strip_of(y_min)], 1);
    }
    __syncthreads();
    if (tid < NSTRIP) {
        int c = lh[tid];
        lbase[tid] = c ? (int)atomicAdd(&strip_count[tid], (unsigned int)c) : 0;
        lh[tid] = 0;
    }
    __syncthreads();
    // pass 2: full box, payload write at reserved slot
    for (int i = lo + tid; i < hi; i += 256) {
        float x_min, y_min, hx, hy;
        node_box(pos, nsx, nsy, i, x_min, y_min, hx, hy);
        float density = pw[i] / (4.0f * hx * hy);
        int s = strip_of(y_min);
        int p = s * SCAP + lbase[s] + atomicAdd(&lh[s], 1);
        pay[p] = make_float4(x_min, y_min, pack_hxy(hx, hy), density);
    }
}

// K2: strip scatter — fixed-point u32 accumulator, col-major [col][10 rows],
// each column's 2-3 consecutive-row contributions fused into 1-2 ds_add_u64.
__global__ __launch_bounds__(SCAT_THREADS) void strip_scatter_kernel(
        const float4* __restrict__ pay, const unsigned int* __restrict__ strip_count,
        unsigned int* __restrict__ partial) {
    __shared__ unsigned int lacc[SCELLS];
    int tid = threadIdx.x;
    int s = blockIdx.x >> 3, r = blockIdx.x & (RREP - 1);
    for (int j = tid; j < SCELLS; j += SCAT_THREADS) lacc[j] = 0u;
    __syncthreads();
    unsigned int lds_base = (unsigned int)(uintptr_t)&lacc[0];
    int lo0 = s * SCAP;
    int count = (int)strip_count[s];
    int lo = lo0 + (int)(((long long)count * r) / RREP);
    int hi = lo0 + (int)(((long long)count * (r + 1)) / RREP);
    int row0 = s * SROWS;

    for (int p = lo + tid; p < hi; p += SCAT_THREADS) {
        float4 g = pay[p];
        float x_min = g.x, y_min = g.y, den = g.w;
        float hx, hy;
        unpack_hxy(g.z, hx, hy);
        float x_max = x_min + 2.0f * hx;
        float y_max = y_min + 2.0f * hy;
        int bxl = (int)floorf(x_min / BSX);
        int byl = (int)floorf(y_min / BSX);
        int L0 = byl - row0;
        if ((unsigned)L0 > 7u) continue;   // memory-safety guard

        // row overlaps (oy0, oy1 always > 0 for interior nodes; oy2 may be <=0)
        float oy0 = (float)(byl + 1) * BSX - y_min;
        float oy1 = fminf(y_max - (float)(byl + 1) * BSX, BSX);
        float oy2 = y_max - (float)(byl + 2) * BSX;
        float qs = den * 65536.0f;
        float f0 = oy0 * qs;
        float f1 = oy1 * qs;
        float f2 = fmaxf(oy2, 0.0f) * qs;
        // col overlaps
        float ox0 = (float)(bxl + 1) * BSX - x_min;
        float ox1 = fminf(x_max - (float)(bxl + 1) * BSX, BSX);
        float ox2 = x_max - (float)(bxl + 2) * BSX;

        bool odd = (L0 & 1) != 0;
        unsigned int base0 = lds_base + (unsigned int)((L0 >> 1) * 8);

        #define DO_COL(ox_, ix_) {                                             \
            unsigned int u0 = (unsigned int)((ox_) * f0 + 0.5f);               \
            unsigned int u1 = (unsigned int)((ox_) * f1 + 0.5f);               \
            unsigned int u2 = (unsigned int)((ox_) * f2 + 0.5f);               \
            unsigned long long A, B;                                           \
            if (!odd) { A = (unsigned long long)u0 |                           \
                            ((unsigned long long)u1 << 32);                    \
                        B = (unsigned long long)u2; }                          \
            else      { A = ((unsigned long long)u0) << 32;                    \
                        B = (unsigned long long)u1 |                           \
                            ((unsigned long long)u2 << 32); }                  \
            unsigned int offA = base0 + (unsigned int)(ix_) * 40u;             \
            asm volatile("ds_add_u64 %0, %1" :: "v"(offA), "v"(A));            \
            if (B) asm volatile("ds_add_u64 %0, %1" :: "v"(offA + 8u), "v"(B)); }

        if ((unsigned)bxl < (unsigned)NBX)       DO_COL(ox0, bxl);
        if ((unsigned)(bxl + 1) < (unsigned)NBX) DO_COL(ox1, bxl + 1);
        if (ox2 > 0.0f && (unsigned)(bxl + 2) < (unsigned)NBX) DO_COL(ox2, bxl + 2);
        #undef DO_COL
    }

    // drain all outstanding ds_add ops, then make them visible to the block
    asm volatile("s_waitcnt lgkmcnt(0)" ::: "memory");
    __syncthreads();
    // transpose to row-major [row][col] on writeback so K3 reads coalesced
    unsigned int* dst = partial + (size_t)blockIdx.x * SCELLS;
    for (int j = tid; j < SCELLS; j += SCAT_THREADS) {
        int row = j >> 9, col = j & (NBX - 1);
        dst[j] = lacc[col * LROWS + row];
    }
}

// K3: gather replicas + y-halo (u32 exact sums), dequant, clip; transpose via
// LDS so both partial reads (contiguous x) and out writes ([x][y]) coalesce
__global__ __launch_bounds__(1024) void final_kernel(
        const unsigned int* __restrict__ partial, float* __restrict__ out) {
    __shared__ float tile[32][33];
    int tx = threadIdx.x, ty = threadIdx.y;
    int x0 = blockIdx.x * 32, y0 = blockIdx.y * 32;
    int x = x0 + tx;          // x-bin (contiguous over lanes)
    int gy = y0 + ty;         // y-bin
    int s = gy >> 3, L = gy & 7;
    unsigned int sum = 0u;
    #pragma unroll
    for (int r = 0; r < RREP; ++r)
        sum += partial[(size_t)(s * RREP + r) * SCELLS + L * NBX + x];
    if (L < 2 && s > 0) {
        #pragma unroll
        for (int r = 0; r < RREP; ++r)
            sum += partial[(size_t)((s - 1) * RREP + r) * SCELLS + (L + SROWS) * NBX + x];
    }
    float u = (float)sum * INV_Q_NORM;
    tile[ty][tx] = fminf(fmaxf(u, MIN_RATE), MAX_RATE);
    __syncthreads();
    out[(x0 + ty) * NBY + (y0 + tx)] = tile[tx][ty];
}

// ---------------- fallback path (proven) ----------------

__global__ void zero_acc_kernel(float* __restrict__ acc, int n) {
    int i = blockIdx.x * blockDim.x + threadIdx.x;
    if (i < n) acc[i] = 0.0f;
}

__global__ __launch_bounds__(256) void pin_scatter_kernel(
        const float* __restrict__ pos, const float* __restrict__ nsx,
        const float* __restrict__ nsy, const float* __restrict__ pw,
        float* __restrict__ acc) {
    int i = blockIdx.x * blockDim.x + threadIdx.x;
    if (i >= NUM_PHYSICAL) return;
    float x_min, y_min, hx, hy;
    node_box(pos, nsx, nsy, i, x_min, y_min, hx, hy);
    float x_max = x_min + 2.0f * hx, y_max = y_min + 2.0f * hy;
    float density = pw[i] / (4.0f * hx * hy);
    int bxl = (int)floorf(x_min / BSX);
    int byl = (int)floorf(y_min / BSX);
    #pragma unroll
    for (int kx = 0; kx < 3; ++kx) {
        int ix = bxl + kx;
        float bx_lo = (float)ix * BSX;
        float ox = fminf(x_max, bx_lo + BSX) - fmaxf(x_min, bx_lo);
        if (ix < 0 || ix >= NBX || !(ox > 0.0f)) continue;
        #pragma unroll
        for (int ky = 0; ky < 3; ++ky) {
            int iy = byl + ky;
            float by_lo = (float)iy * BSX;
            float oy = fminf(y_max, by_lo + BSX) - fmaxf(y_min, by_lo);
            if (iy >= 0 && iy < NBY && oy > 0.0f)
                atomicAdd(&acc[ix * NBY + iy], ox * oy * density);
        }
    }
}

__global__ void finalize_kernel(float* __restrict__ out, int n) {
    int i = blockIdx.x * blockDim.x + threadIdx.x;
    if (i < n) {
        float u = out[i] / NORM_DIV;
        out[i] = fminf(fmaxf(u, MIN_RATE), MAX_RATE);
    }
}

extern "C" void kernel_launch(void* const* d_in, const int* in_sizes, int n_in,
                              void* d_out, int out_size, void* d_ws, size_t ws_size,
                              hipStream_t stream) {
    const float* pos = (const float*)d_in[0];
    const float* nsx = (const float*)d_in[1];
    const float* nsy = (const float*)d_in[2];
    const float* pw  = (const float*)d_in[3];
    float* out = (float*)d_out;

    // workspace layout (bytes)
    const size_t OFF_PAY  = 0;                                     // NSTRIP*SCAP*16 = 50,331,648
    const size_t OFF_CNT  = (size_t)NSTRIP * SCAP * 16;            // 64 u32 = 256
    const size_t OFF_PART = (OFF_CNT + NSTRIP * 4 + 255) & ~(size_t)255;
    const size_t WS_NEEDED = OFF_PART + (size_t)SCAT_BLOCKS * SCELLS * 4; // ~60.8 MB

    if (ws_size >= WS_NEEDED) {
        char* w = (char*)d_ws;
        float4*       pay     = (float4*)      (w + OFF_PAY);
        unsigned int* cnt     = (unsigned int*)(w + OFF_CNT);
        unsigned int* partial = (unsigned int*)(w + OFF_PART);

        // zero the 64 strip cursors (graph-capturable, every launch)
        hipMemsetAsync(cnt, 0, NSTRIP * sizeof(unsigned int), stream);

        place_fused_kernel<<<HB, 256, 0, stream>>>(pos, nsx, nsy, pw, cnt, pay);
        strip_scatter_kernel<<<SCAT_BLOCKS, SCAT_THREADS, 0, stream>>>(
            pay, cnt, partial);
        final_kernel<<<dim3(NBX / 32, NBY / 32), dim3(32, 32), 0, stream>>>(partial, out);
    } else {
        zero_acc_kernel<<<(NBINS + 255) / 256, 256, 0, stream>>>(out, NBINS);
        pin_scatter_kernel<<<(NUM_PHYSICAL + 255) / 256, 256, 0, stream>>>(
            pos, nsx, nsy, pw, out);
        finalize_kernel<<<(NBINS + 255) / 256, 256, 0, stream>>>(out, NBINS);
    }
}

// Round 11
// 59.747 us; speedup vs baseline: 1.0018x; 1.0018x over previous
//
#include <hip/hip_runtime.h>
#include <hip/hip_fp16.h>

// Problem constants (must match reference)
#define NUM_PHYSICAL 2000000
#define NUM_NODES    2500000   // 2,000,000 physical + 500,000 filler
#define NBX 512
#define NBY 512
#define NBINS (NBX * NBY)

// BSX = BSY = 1000/512 = 1.953125 (exact in binary)
#define BSX 1.953125f
#define HALF_STRETCH ((float)(0.5 * 1.953125 * 1.4142135623730951))
// BSX*BSY*UNIT_PIN_CAPACITY = 61.03515625 (exact); x 65536 = 4,000,000 exactly
#define INV_Q_NORM (1.0f / 4000000.0f)
#define NORM_DIV 61.03515625f
#define MAX_RATE 2.5f
#define MIN_RATE 0.4f   // 1/2.5 exactly

// Strip bucketing: 64 strips of 8 y-rows, each split into 8 cursor groups.
#define NSTRIP 64
#define NGRP 8
#define NSEG (NSTRIP * NGRP)     // 512 segments
#define SCAP 4352                // slots per segment (mean 3906, +7 sigma)
#define MAXSLOT (NSEG * SCAP - 1)
#define SROWS 8                  // rows per strip
#define LROWS 10                 // 8 + 2 y-halo (node spans <=3 rows)
#define SCELLS (NBX * LROWS)     // 5120 u32 = 20 KB LDS, col-major [col][row]
#define SCAT_THREADS 1024
#define HB 1024                  // blocks for fused placement
#define CHUNK ((NUM_PHYSICAL + HB - 1) / HB)   // 1954

__device__ __forceinline__ int strip_of(float y_min) {
    int byl = (int)floorf(y_min / BSX);
    return (min(max(byl, 0), NBY - 1)) >> 3;
}

__device__ __forceinline__ void node_box(const float* __restrict__ pos,
                                         const float* __restrict__ nsx,
                                         const float* __restrict__ nsy, int i,
                                         float& x_min, float& y_min,
                                         float& hx, float& hy) {
    float sx = nsx[i], sy = nsy[i];
    hx = 0.5f * fmaxf(sx, 2.0f * HALF_STRETCH);
    hy = 0.5f * fmaxf(sy, 2.0f * HALF_STRETCH);
    x_min = (pos[i]             + 0.5f * sx) - hx;
    y_min = (pos[NUM_NODES + i] + 0.5f * sy) - hy;
}

__device__ __forceinline__ float pack_hxy(float hx, float hy) {
    unsigned int u = ((unsigned int)__half_as_ushort(__float2half_rn(hy)) << 16)
                   |  (unsigned int)__half_as_ushort(__float2half_rn(hx));
    return __uint_as_float(u);
}
__device__ __forceinline__ void unpack_hxy(float p, float& hx, float& hy) {
    unsigned int u = __float_as_uint(p);
    hx = __half2float(__ushort_as_half((unsigned short)(u & 0xffffu)));
    hy = __half2float(__ushort_as_half((unsigned short)(u >> 16)));
}

// ---------------- sorted-strip path ----------------

// K1 (fused hist+place, contention-free reservation): pass 1 builds the
// per-block strip histogram; ONE global atomicAdd per strip into this
// block's GROUP counter (512 counters, per-address chains ~128) reserves a
// contiguous slice of segment (strip, grp); pass 2 writes 16B payloads.
// Payload order is nondeterministic across blocks, but downstream
// accumulation is integer (exact, commutative) -> d_out bit-deterministic.
__global__ __launch_bounds__(256) void place_direct_kernel(
        const float* __restrict__ pos, const float* __restrict__ nsx,
        const float* __restrict__ nsy, const float* __restrict__ pw,
        unsigned int* __restrict__ seg_count,   // [NSEG], pre-zeroed
        float4* __restrict__ pay) {
    __shared__ int lh[NSTRIP];     // pass1: counts; pass2: local cursor
    __shared__ int lbase[NSTRIP];  // reserved base within segment (s, grp)
    int tid = threadIdx.x, b = blockIdx.x;
    int grp = b & (NGRP - 1);
    if (tid < NSTRIP) lh[tid] = 0;
    __syncthreads();
    int lo = b * CHUNK, hi = min(lo + CHUNK, NUM_PHYSICAL);
    // pass 1: strip id needs only y data (chunk stays L1-resident for pass 2)
    for (int i = lo + tid; i < hi; i += 256) {
        float sy = nsy[i];
        float hy = 0.5f * fmaxf(sy, 2.0f * HALF_STRETCH);
        float y_min = (pos[NUM_NODES + i] + 0.5f * sy) - hy;
        atomicAdd(&lh[strip_of(y_min)], 1);
    }
    __syncthreads();
    if (tid < NSTRIP) {
        int c = lh[tid];
        lbase[tid] = c ? (int)atomicAdd(&seg_count[tid * NGRP + grp],
                                        (unsigned int)c) : 0;
        lh[tid] = 0;
    }
    __syncthreads();
    // pass 2: full box, payload write at reserved slot
    for (int i = lo + tid; i < hi; i += 256) {
        float x_min, y_min, hx, hy;
        node_box(pos, nsx, nsy, i, x_min, y_min, hx, hy);
        float density = pw[i] / (4.0f * hx * hy);
        int s = strip_of(y_min);
        int idx = atomicAdd(&lh[s], 1);
        int slot = (s * NGRP + grp) * SCAP + lbase[s] + idx;
        slot = min(slot, MAXSLOT);   // memory-safety (overflow ~1e-12/segment)
        pay[slot] = make_float4(x_min, y_min, pack_hxy(hx, hy), density);
    }
}

// K2: segment scatter — one block per (strip, grp) segment. Fixed-point u32
// accumulator, col-major [col][10 rows]; each column's 2-3 consecutive-row
// contributions fused into 1-2 ds_add_u64.
__global__ __launch_bounds__(SCAT_THREADS) void strip_scatter_kernel(
        const float4* __restrict__ pay, const unsigned int* __restrict__ seg_count,
        unsigned int* __restrict__ partial) {
    __shared__ unsigned int lacc[SCELLS];
    int tid = threadIdx.x;
    int seg = blockIdx.x;
    int s = seg >> 3;              // strip
    for (int j = tid; j < SCELLS; j += SCAT_THREADS) lacc[j] = 0u;
    __syncthreads();
    unsigned int lds_base = (unsigned int)(uintptr_t)&lacc[0];
    int lo = seg * SCAP;
    int hi = lo + min((int)seg_count[seg], SCAP);
    int row0 = s * SROWS;

    for (int p = lo + tid; p < hi; p += SCAT_THREADS) {
        float4 g = pay[p];
        float x_min = g.x, y_min = g.y, den = g.w;
        float hx, hy;
        unpack_hxy(g.z, hx, hy);
        float x_max = x_min + 2.0f * hx;
        float y_max = y_min + 2.0f * hy;
        int bxl = (int)floorf(x_min / BSX);
        int byl = (int)floorf(y_min / BSX);
        int L0 = byl - row0;
        if ((unsigned)L0 > 7u) continue;   // memory-safety guard

        // row overlaps (oy0, oy1 always > 0 for interior nodes; oy2 may be <=0)
        float oy0 = (float)(byl + 1) * BSX - y_min;
        float oy1 = fminf(y_max - (float)(byl + 1) * BSX, BSX);
        float oy2 = y_max - (float)(byl + 2) * BSX;
        float qs = den * 65536.0f;
        float f0 = oy0 * qs;
        float f1 = oy1 * qs;
        float f2 = fmaxf(oy2, 0.0f) * qs;
        // col overlaps
        float ox0 = (float)(bxl + 1) * BSX - x_min;
        float ox1 = fminf(x_max - (float)(bxl + 1) * BSX, BSX);
        float ox2 = x_max - (float)(bxl + 2) * BSX;

        bool odd = (L0 & 1) != 0;
        unsigned int base0 = lds_base + (unsigned int)((L0 >> 1) * 8);

        #define DO_COL(ox_, ix_) {                                             \
            unsigned int u0 = (unsigned int)((ox_) * f0 + 0.5f);               \
            unsigned int u1 = (unsigned int)((ox_) * f1 + 0.5f);               \
            unsigned int u2 = (unsigned int)((ox_) * f2 + 0.5f);               \
            unsigned long long A, B;                                           \
            if (!odd) { A = (unsigned long long)u0 |                           \
                            ((unsigned long long)u1 << 32);                    \
                        B = (unsigned long long)u2; }                          \
            else      { A = ((unsigned long long)u0) << 32;                    \
                        B = (unsigned long long)u1 |                           \
                            ((unsigned long long)u2 << 32); }                  \
            unsigned int offA = base0 + (unsigned int)(ix_) * 40u;             \
            asm volatile("ds_add_u64 %0, %1" :: "v"(offA), "v"(A));            \
            if (B) asm volatile("ds_add_u64 %0, %1" :: "v"(offA + 8u), "v"(B)); }

        if ((unsigned)bxl < (unsigned)NBX)       DO_COL(ox0, bxl);
        if ((unsigned)(bxl + 1) < (unsigned)NBX) DO_COL(ox1, bxl + 1);
        if (ox2 > 0.0f && (unsigned)(bxl + 2) < (unsigned)NBX) DO_COL(ox2, bxl + 2);
        #undef DO_COL
    }

    // drain all outstanding ds_add ops, then make them visible to the block
    asm volatile("s_waitcnt lgkmcnt(0)" ::: "memory");
    __syncthreads();
    // transpose to row-major [row][col] on writeback so K3 reads coalesced
    unsigned int* dst = partial + (size_t)blockIdx.x * SCELLS;
    for (int j = tid; j < SCELLS; j += SCAT_THREADS) {
        int row = j >> 9, col = j & (NBX - 1);
        dst[j] = lacc[col * LROWS + row];
    }
}

// K3: gather the 8 group-partials + y-halo (u32 exact sums), dequant, clip;
// transpose via LDS so partial reads and out writes both coalesce
__global__ __launch_bounds__(1024) void final_kernel(
        const unsigned int* __restrict__ partial, float* __restrict__ out) {
    __shared__ float tile[32][33];
    int tx = threadIdx.x, ty = threadIdx.y;
    int x0 = blockIdx.x * 32, y0 = blockIdx.y * 32;
    int x = x0 + tx;          // x-bin (contiguous over lanes)
    int gy = y0 + ty;         // y-bin
    int s = gy >> 3, L = gy & 7;
    unsigned int sum = 0u;
    #pragma unroll
    for (int r = 0; r < NGRP; ++r)
        sum += partial[(size_t)(s * NGRP + r) * SCELLS + L * NBX + x];
    if (L < 2 && s > 0) {
        #pragma unroll
        for (int r = 0; r < NGRP; ++r)
            sum += partial[(size_t)((s - 1) * NGRP + r) * SCELLS + (L + SROWS) * NBX + x];
    }
    float u = (float)sum * INV_Q_NORM;
    tile[ty][tx] = fminf(fmaxf(u, MIN_RATE), MAX_RATE);
    __syncthreads();
    out[(x0 + ty) * NBY + (y0 + tx)] = tile[tx][ty];
}

// ---------------- fallback path (proven) ----------------

__global__ void zero_acc_kernel(float* __restrict__ acc, int n) {
    int i = blockIdx.x * blockDim.x + threadIdx.x;
    if (i < n) acc[i] = 0.0f;
}

__global__ __launch_bounds__(256) void pin_scatter_kernel(
        const float* __restrict__ pos, const float* __restrict__ nsx,
        const float* __restrict__ nsy, const float* __restrict__ pw,
        float* __restrict__ acc) {
    int i = blockIdx.x * blockDim.x + threadIdx.x;
    if (i >= NUM_PHYSICAL) return;
    float x_min, y_min, hx, hy;
    node_box(pos, nsx, nsy, i, x_min, y_min, hx, hy);
    float x_max = x_min + 2.0f * hx, y_max = y_min + 2.0f * hy;
    float density = pw[i] / (4.0f * hx * hy);
    int bxl = (int)floorf(x_min / BSX);
    int byl = (int)floorf(y_min / BSX);
    #pragma unroll
    for (int kx = 0; kx < 3; ++kx) {
        int ix = bxl + kx;
        float bx_lo = (float)ix * BSX;
        float ox = fminf(x_max, bx_lo + BSX) - fmaxf(x_min, bx_lo);
        if (ix < 0 || ix >= NBX || !(ox > 0.0f)) continue;
        #pragma unroll
        for (int ky = 0; ky < 3; ++ky) {
            int iy = byl + ky;
            float by_lo = (float)iy * BSX;
            float oy = fminf(y_max, by_lo + BSX) - fmaxf(y_min, by_lo);
            if (iy >= 0 && iy < NBY && oy > 0.0f)
                atomicAdd(&acc[ix * NBY + iy], ox * oy * density);
        }
    }
}

__global__ void finalize_kernel(float* __restrict__ out, int n) {
    int i = blockIdx.x * blockDim.x + threadIdx.x;
    if (i < n) {
        float u = out[i] / NORM_DIV;
        out[i] = fminf(fmaxf(u, MIN_RATE), MAX_RATE);
    }
}

extern "C" void kernel_launch(void* const* d_in, const int* in_sizes, int n_in,
                              void* d_out, int out_size, void* d_ws, size_t ws_size,
                              hipStream_t stream) {
    const float* pos = (const float*)d_in[0];
    const float* nsx = (const float*)d_in[1];
    const float* nsy = (const float*)d_in[2];
    const float* pw  = (const float*)d_in[3];
    float* out = (float*)d_out;

    // workspace layout (bytes)
    const size_t OFF_PAY  = 0;                               // NSEG*SCAP*16 = 35,651,584
    const size_t OFF_CNT  = (size_t)NSEG * SCAP * 16;        // NSEG u32 = 2,048
    const size_t OFF_PART = (OFF_CNT + NSEG * 4 + 255) & ~(size_t)255;
    const size_t WS_NEEDED = OFF_PART + (size_t)NSEG * SCELLS * 4; // ~46.1 MB

    if (ws_size >= WS_NEEDED) {
        char* w = (char*)d_ws;
        float4*       pay     = (float4*)      (w + OFF_PAY);
        unsigned int* cnt     = (unsigned int*)(w + OFF_CNT);
        unsigned int* partial = (unsigned int*)(w + OFF_PART);

        // zero the 512 segment cursors (graph-capturable, every launch)
        hipMemsetAsync(cnt, 0, NSEG * sizeof(unsigned int), stream);

        place_direct_kernel<<<HB, 256, 0, stream>>>(pos, nsx, nsy, pw, cnt, pay);
        strip_scatter_kernel<<<NSEG, SCAT_THREADS, 0, stream>>>(pay, cnt, partial);
        final_kernel<<<dim3(NBX / 32, NBY / 32), dim3(32, 32), 0, stream>>>(partial, out);
    } else {
        zero_acc_kernel<<<(NBINS + 255) / 256, 256, 0, stream>>>(out, NBINS);
        pin_scatter_kernel<<<(NUM_PHYSICAL + 255) / 256, 256, 0, stream>>>(
            pos, nsx, nsy, pw, out);
        finalize_kernel<<<(NBINS + 255) / 256, 256, 0, stream>>>(out, NBINS);
    }
}